// Round 3
// baseline (1562.837 us; speedup 1.0000x reference)
//
#include <hip/hip_runtime.h>

typedef unsigned short u16;
typedef unsigned int   u32;
typedef __attribute__((ext_vector_type(8))) __bf16 bf16x8;
typedef __attribute__((ext_vector_type(4))) float  f32x4;

#define DEV __device__ __forceinline__

static constexpr int NN = 30000;
static constexpr int NE = 480000;
static constexpr int DD = 512;

static constexpr long OUT_FUSED = 0;
static constexpr long OUT_H     = 9000000;
static constexpr long OUT_IMG   = 24360000;
static constexpr long OUT_ATTR  = 33360000;
static constexpr long OUT_REL   = 42360000;

DEV float bf2f(u32 u){ u32 v = u << 16; float f; __builtin_memcpy(&f, &v, 4); return f; }
DEV u16 f2bf(float f){ u32 u; __builtin_memcpy(&u, &f, 4); u = (u + 0x7fffu + ((u >> 16) & 1u)) >> 16; return (u16)u; }
DEV u32 pk2(float a, float b){ return (u32)f2bf(a) | ((u32)f2bf(b) << 16); }

// ---------------- CSR build ----------------
__global__ void k_hist(const int* __restrict__ dst, int* __restrict__ deg){
  int e = blockIdx.x * 256 + threadIdx.x;
  if (e < NE) atomicAdd(&deg[dst[e]], 1);
}

__global__ void k_scan(const int* __restrict__ deg, int* __restrict__ rp, float* __restrict__ invd){
  __shared__ int sh[1024];
  __shared__ int carry_s;
  const int tid = threadIdx.x;
  if (tid == 0) carry_s = 0;
  __syncthreads();
  for (int base = 0; base < NN; base += 1024){
    int i = base + tid;
    int v = (i < NN) ? deg[i] : 0;
    sh[tid] = v;
    __syncthreads();
    for (int off = 1; off < 1024; off <<= 1){
      int t = (tid >= off) ? sh[tid - off] : 0;
      __syncthreads();
      sh[tid] += t;
      __syncthreads();
    }
    int incl = sh[tid];
    int c = carry_s;
    if (i < NN){
      rp[i]   = c + incl - v;
      invd[i] = 1.0f / (float)(v > 1 ? v : 1);
    }
    __syncthreads();
    if (tid == 1023) carry_s = c + incl;
    __syncthreads();
  }
  if (tid == 0) rp[NN] = carry_s;
}

__global__ void k_scatter(const int* __restrict__ src, const int* __restrict__ dst,
                          const int* __restrict__ rp, int* __restrict__ cur, int* __restrict__ col){
  int e = blockIdx.x * 256 + threadIdx.x;
  if (e >= NE) return;
  int d = dst[e];
  int p = atomicAdd(&cur[d], 1);
  col[rp[d] + p] = src[e];
}

// ---------------- converts ----------------
__global__ void k_cvt(const float* __restrict__ src, u16* __restrict__ dst, const int n8){
  int i = blockIdx.x * 256 + threadIdx.x;
  if (i >= n8) return;
  const float4* s4 = (const float4*)src;
  float4 p = s4[2*i], q = s4[2*i+1];
  uint4 o; o.x = pk2(p.x,p.y); o.y = pk2(p.z,p.w); o.z = pk2(q.x,q.y); o.w = pk2(q.z,q.w);
  ((uint4*)dst)[i] = o;
}

__global__ void k_cvt_pad(const float* __restrict__ src, u16* __restrict__ dst,
                          const int rows, const int K, const int total, const int Kp){
  int i = blockIdx.x * 256 + threadIdx.x;
  if (i >= total) return;
  int r = i / Kp, k = i - r * Kp;
  float v = (r < rows && k < K) ? src[r * K + k] : 0.f;
  dst[i] = f2bf(v);
}

// ---------------- mean aggregation (one wave per node) ----------------
__global__ __launch_bounds__(256) void k_agg(const u16* __restrict__ Xb, const int* __restrict__ rp,
        const int* __restrict__ cols, const float* __restrict__ invd, u16* __restrict__ aggb)
{
  const int node = blockIdx.x * 4 + (threadIdx.x >> 6);
  const int l = threadIdx.x & 63;
  const int beg = rp[node], end = rp[node + 1];
  float a0=0,a1=0,a2=0,a3=0,a4=0,a5=0,a6=0,a7=0;
  const uint4* X4 = (const uint4*)Xb;
  for (int e = beg; e < end; ++e){
    const int s = cols[e];
    uint4 v = X4[s * 64 + l];
    a0 += bf2f(v.x & 0xffffu); a1 += bf2f(v.x >> 16);
    a2 += bf2f(v.y & 0xffffu); a3 += bf2f(v.y >> 16);
    a4 += bf2f(v.z & 0xffffu); a5 += bf2f(v.z >> 16);
    a6 += bf2f(v.w & 0xffffu); a7 += bf2f(v.w >> 16);
  }
  const float sc = invd[node];
  uint4 o;
  o.x = pk2(a0*sc, a1*sc); o.y = pk2(a2*sc, a3*sc);
  o.z = pk2(a4*sc, a5*sc); o.w = pk2(a6*sc, a7*sc);
  ((uint4*)aggb)[node * 64 + l] = o;
}

// swizzled 16B-group offset within a 32-u16 (64B) LDS row: 2-way-max bank conflicts
DEV int swz(int row, int g){ return row * 32 + ((g ^ ((row >> 1) & 3)) * 8); }

// ---------------- SAGE GEMM: C[M,512] = A1@W1^T + A2@W2^T + bias (opt relu) ----------------
// 128x128 tile, BK=32, reg-staged A/B (issue-early, ds_write-late), 2-deep pipeline.
__global__ __launch_bounds__(256) void k_sage_gemm(
    const u16* __restrict__ A1, const u16* __restrict__ W1,
    const u16* __restrict__ A2, const u16* __restrict__ W2,
    const float* __restrict__ bias,
    u16* __restrict__ outB, float* __restrict__ outF, const int relu)
{
  __shared__ u16 lA[2][128 * 32];
  __shared__ u16 lB[2][128 * 32];
  const int tid = threadIdx.x;
  const int w = tid >> 6, l = tid & 63;
  const int brow = blockIdx.x * 128, bcol = blockIdx.y * 128;

  f32x4 acc[4][4];
  #pragma unroll
  for (int i = 0; i < 4; ++i)
    #pragma unroll
    for (int j = 0; j < 4; ++j) acc[i][j] = {0.f, 0.f, 0.f, 0.f};

  // staging slots: slot = tid + 256*is, is=0..1; row = slot>>2, group = slot&3
  int ar[2], ag[2];
  #pragma unroll
  for (int is = 0; is < 2; ++is){ int s = tid + 256 * is; ar[is] = s >> 2; ag[is] = s & 3; }
  int grA[2], grB[2];
  #pragma unroll
  for (int is = 0; is < 2; ++is){
    int g = brow + ar[is]; if (g >= NN) g = NN - 1;
    grA[is] = g;
    grB[is] = bcol + ar[is];
  }

  struct RS { uint4 a[2]; uint4 b[2]; };
  RS r0, r1;

  auto L = [&](RS& rs, int kt){
    const u16 *A, *W; int kk;
    if (kt < 16){ A = A1; W = W1; kk = kt * 32; } else { A = A2; W = W2; kk = (kt - 16) * 32; }
    #pragma unroll
    for (int is = 0; is < 2; ++is){
      rs.a[is] = *(const uint4*)(A + (size_t)grA[is] * DD + kk + ag[is] * 8);
      rs.b[is] = *(const uint4*)(W + (size_t)grB[is] * DD + kk + ag[is] * 8);
    }
  };
  auto Wr = [&](RS& rs, int buf){
    #pragma unroll
    for (int is = 0; is < 2; ++is){
      *(uint4*)&lA[buf][swz(ar[is], ag[is])] = rs.a[is];
      *(uint4*)&lB[buf][swz(ar[is], ag[is])] = rs.b[is];
    }
  };
  auto C = [&](int buf){
    bf16x8 a[4], b[4];
    #pragma unroll
    for (int i = 0; i < 4; ++i){
      const int r = (w & 1) * 64 + i * 16 + (l & 15);
      a[i] = *(const bf16x8*)&lA[buf][swz(r, l >> 4)];
    }
    #pragma unroll
    for (int j = 0; j < 4; ++j){
      const int r = (w >> 1) * 64 + j * 16 + (l & 15);
      b[j] = *(const bf16x8*)&lB[buf][swz(r, l >> 4)];
    }
    #pragma unroll
    for (int i = 0; i < 4; ++i)
      #pragma unroll
      for (int j = 0; j < 4; ++j)
        acc[i][j] = __builtin_amdgcn_mfma_f32_16x16x32_bf16(a[i], b[j], acc[i][j], 0, 0, 0);
  };

  const int NT = 32;
  L(r0, 0); L(r1, 1);
  Wr(r0, 0);
  __syncthreads();
  for (int t = 0; t < NT; t += 2){
    if (t + 2 < NT) L(r0, t + 2);
    C(0);
    Wr(r1, 1);
    __syncthreads();
    if (t + 3 < NT) L(r1, t + 3);
    C(1);
    if (t + 2 < NT) Wr(r0, 0);
    __syncthreads();
  }

  const int wm = (w & 1) * 64, wn = (w >> 1) * 64;
  #pragma unroll
  for (int j = 0; j < 4; ++j){
    const int col = bcol + wn + j * 16 + (l & 15);
    const float bv = bias[col];
    #pragma unroll
    for (int i = 0; i < 4; ++i){
      const int row0 = brow + wm + i * 16 + ((l >> 4) << 2);
      #pragma unroll
      for (int r = 0; r < 4; ++r){
        const int row = row0 + r;
        if (row < NN){
          float v = acc[i][j][r] + bv;
          if (relu) v = fmaxf(v, 0.f);
          outB[(size_t)row * DD + col] = f2bf(v);
          if (outF) outF[(size_t)row * DD + col] = v;
        }
      }
    }
  }
}

// ---------------- Fusion GEMM: C[M,300] = A@W^T + bias ----------------
// BM=64, BN=192, BK=32, 4 waves. Reg-staged A and B, 2-deep pipeline.
// AKIND 0: f32 A; AKIND 1: bf16 A.
template<int AKIND>
__global__ __launch_bounds__(256) void k_fuse_gemm(
    const void* __restrict__ Asrc, const int K, const int Kp,
    const u16* __restrict__ Wp, const float* __restrict__ bias, float* __restrict__ outC)
{
  __shared__ u16 lA[2][64 * 32];
  __shared__ u16 lB[2][192 * 32];
  const int tid = threadIdx.x;
  const int w = tid >> 6, l = tid & 63;
  const int brow = blockIdx.x * 64;
  const int bcol = blockIdx.y * 192;
  const int NT = Kp >> 5;

  f32x4 acc[4][3];
  #pragma unroll
  for (int i = 0; i < 4; ++i)
    #pragma unroll
    for (int j = 0; j < 3; ++j) acc[i][j] = {0.f, 0.f, 0.f, 0.f};

  // A slot: row = tid>>2 (0..63), group = tid&3
  const int arow = tid >> 2, agr = tid & 3;
  int garow = brow + arow; if (garow >= NN) garow = NN - 1;
  // B slots: slot = tid + 256*is, is=0..2; row = slot>>2 (0..191), group = slot&3
  int br[3], bg[3];
  #pragma unroll
  for (int is = 0; is < 3; ++is){ int s = tid + 256 * is; br[is] = s >> 2; bg[is] = s & 3; }

  struct RS { float af[8]; uint4 ab; uint4 b[3]; };
  RS r0, r1;

  auto L = [&](RS& rs, int kt){
    const int kk = kt * 32;
    if (AKIND == 0){
      const float* A = (const float*)Asrc + (size_t)garow * K;
      const int k0 = kk + agr * 8;
      if (k0 + 8 <= K){
        float4 p = *(const float4*)(A + k0);
        float4 q = *(const float4*)(A + k0 + 4);
        rs.af[0]=p.x; rs.af[1]=p.y; rs.af[2]=p.z; rs.af[3]=p.w;
        rs.af[4]=q.x; rs.af[5]=q.y; rs.af[6]=q.z; rs.af[7]=q.w;
      } else {
        #pragma unroll
        for (int t = 0; t < 8; ++t){ int k = k0 + t; rs.af[t] = (k < K) ? A[k] : 0.f; }
      }
    } else {
      rs.ab = *(const uint4*)((const u16*)Asrc + (size_t)garow * Kp + kk + agr * 8);
    }
    #pragma unroll
    for (int is = 0; is < 3; ++is)
      rs.b[is] = *(const uint4*)(Wp + (size_t)(bcol + br[is]) * Kp + kk + bg[is] * 8);
  };
  auto Wr = [&](RS& rs, int buf){
    uint4 av;
    if (AKIND == 0){
      av.x = pk2(rs.af[0], rs.af[1]); av.y = pk2(rs.af[2], rs.af[3]);
      av.z = pk2(rs.af[4], rs.af[5]); av.w = pk2(rs.af[6], rs.af[7]);
    } else av = rs.ab;
    *(uint4*)&lA[buf][swz(arow, agr)] = av;
    #pragma unroll
    for (int is = 0; is < 3; ++is)
      *(uint4*)&lB[buf][swz(br[is], bg[is])] = rs.b[is];
  };
  auto C = [&](int buf){
    bf16x8 a[4], b[3];
    #pragma unroll
    for (int i = 0; i < 4; ++i){
      const int r = i * 16 + (l & 15);
      a[i] = *(const bf16x8*)&lA[buf][swz(r, l >> 4)];
    }
    #pragma unroll
    for (int j = 0; j < 3; ++j){
      const int r = w * 48 + j * 16 + (l & 15);
      b[j] = *(const bf16x8*)&lB[buf][swz(r, l >> 4)];
    }
    #pragma unroll
    for (int i = 0; i < 4; ++i)
      #pragma unroll
      for (int j = 0; j < 3; ++j)
        acc[i][j] = __builtin_amdgcn_mfma_f32_16x16x32_bf16(a[i], b[j], acc[i][j], 0, 0, 0);
  };

  L(r0, 0); L(r1, 1);
  Wr(r0, 0);
  __syncthreads();
  for (int t = 0; t < NT; t += 2){
    if (t + 2 < NT) L(r0, t + 2);
    C(0);
    Wr(r1, 1);
    __syncthreads();
    if (t + 3 < NT) L(r1, t + 3);
    C(1);
    if (t + 2 < NT) Wr(r0, 0);
    __syncthreads();
  }

  #pragma unroll
  for (int j = 0; j < 3; ++j){
    const int col = bcol + w * 48 + j * 16 + (l & 15);
    if (col < 300){
      const float bv = bias[col];
      #pragma unroll
      for (int i = 0; i < 4; ++i){
        const int row0 = brow + i * 16 + ((l >> 4) << 2);
        #pragma unroll
        for (int r = 0; r < 4; ++r){
          const int row = row0 + r;
          if (row < NN) outC[(size_t)row * 300 + col] = acc[i][j][r] + bv;
        }
      }
    }
  }
}

// ---------------- gates + softmax + weighted sum + L2 norm (one wave per node) ----------------
__global__ __launch_bounds__(256) void k_fuse_final(
    const float* __restrict__ gph, const float* __restrict__ img,
    const float* __restrict__ attr, const float* __restrict__ rel,
    const float* __restrict__ Wfp, const float* __restrict__ bfp,
    float* __restrict__ fused)
{
  const int node = blockIdx.x * 4 + (threadIdx.x >> 6);
  const int l = threadIdx.x & 63;
  const size_t base = (size_t)node * 300;

  float e0[5], e1[5], e2[5], e3[5];
  float p0 = 0, p1 = 0, p2 = 0, p3 = 0;
  #pragma unroll
  for (int s = 0; s < 5; ++s){
    const int c = l + s * 64;
    const bool ok = (c < 300);
    const float wf = ok ? Wfp[c] : 0.f;
    const float a = ok ? gph[base + c]  : 0.f;
    const float b = ok ? img[base + c]  : 0.f;
    const float cc= ok ? attr[base + c] : 0.f;
    const float d = ok ? rel[base + c]  : 0.f;
    e0[s] = a; e1[s] = b; e2[s] = cc; e3[s] = d;
    p0 += wf * a; p1 += wf * b; p2 += wf * cc; p3 += wf * d;
  }
  #pragma unroll
  for (int off = 32; off >= 1; off >>= 1){
    p0 += __shfl_xor(p0, off); p1 += __shfl_xor(p1, off);
    p2 += __shfl_xor(p2, off); p3 += __shfl_xor(p3, off);
  }
  const float bb = bfp[0];
  const float g0 = p0 + bb, g1 = p1 + bb, g2 = p2 + bb, g3 = p3 + bb;
  const float m = fmaxf(fmaxf(g0, g1), fmaxf(g2, g3));
  float w0 = expf(g0 - m), w1 = expf(g1 - m), w2 = expf(g2 - m), w3 = expf(g3 - m);
  const float inv = 1.f / (w0 + w1 + w2 + w3);
  w0 *= inv; w1 *= inv; w2 *= inv; w3 *= inv;

  float f[5]; float nsq = 0;
  #pragma unroll
  for (int s = 0; s < 5; ++s){
    f[s] = w0 * e0[s] + w1 * e1[s] + w2 * e2[s] + w3 * e3[s];
    nsq += f[s] * f[s];
  }
  #pragma unroll
  for (int off = 32; off >= 1; off >>= 1) nsq += __shfl_xor(nsq, off);
  float nrm = sqrtf(nsq); nrm = fmaxf(nrm, 1e-12f);
  const float innv = 1.f / nrm;
  #pragma unroll
  for (int s = 0; s < 5; ++s){
    const int c = l + s * 64;
    if (c < 300) fused[base + c] = f[s] * innv;
  }
}

// ---------------- launch ----------------
extern "C" void kernel_launch(void* const* d_in, const int* in_sizes, int n_in,
                              void* d_out, int out_size, void* d_ws, size_t ws_size,
                              hipStream_t stream) {
  const float* x        = (const float*)d_in[0];
  const int*   ei       = (const int*)  d_in[1];
  const float* img_emb  = (const float*)d_in[2];
  const float* attr_emb = (const float*)d_in[3];
  const float* rel_emb  = (const float*)d_in[4];
  const float* Wl1 = (const float*)d_in[5],  *Wr1 = (const float*)d_in[6],  *b1 = (const float*)d_in[7];
  const float* Wl2 = (const float*)d_in[8],  *Wr2 = (const float*)d_in[9],  *b2 = (const float*)d_in[10];
  const float* Wl3 = (const float*)d_in[11], *Wr3 = (const float*)d_in[12], *b3 = (const float*)d_in[13];
  const float* Wg  = (const float*)d_in[14], *bg  = (const float*)d_in[15];
  const float* Wi  = (const float*)d_in[16], *bi  = (const float*)d_in[17];
  const float* Wa  = (const float*)d_in[18], *ba  = (const float*)d_in[19];
  const float* Wrl = (const float*)d_in[20], *brl = (const float*)d_in[21];
  const float* Wfp = (const float*)d_in[22], *bfp = (const float*)d_in[23];
  float* out = (float*)d_out;

  char* p = (char*)d_ws;
  auto carve = [&](size_t bytes) -> void* {
    void* r = (void*)p;
    p += (bytes + 255) & ~(size_t)255;
    return r;
  };
  int*   deg     = (int*)  carve(NN * 4);
  int*   cursor  = (int*)  carve(NN * 4);
  int*   row_ptr = (int*)  carve((NN + 1) * 4);
  float* inv_deg = (float*)carve(NN * 4);
  int*   csr_col = (int*)  carve(NE * 4);
  u16*   x_bf    = (u16*)  carve((size_t)NN * DD * 2);   // also reused for h3
  u16*   hA      = (u16*)  carve((size_t)NN * DD * 2);
  u16*   hB      = (u16*)  carve((size_t)NN * DD * 2);
  u16*   aggb    = (u16*)  carve((size_t)NN * DD * 2);
  float* gph     = (float*)carve((size_t)NN * 300 * 4);
  u16*   Wl1b = (u16*)carve(512 * 512 * 2);
  u16*   Wr1b = (u16*)carve(512 * 512 * 2);
  u16*   Wl2b = (u16*)carve(512 * 512 * 2);
  u16*   Wr2b = (u16*)carve(512 * 512 * 2);
  u16*   Wl3b = (u16*)carve(512 * 512 * 2);
  u16*   Wr3b = (u16*)carve(512 * 512 * 2);
  u16*   Wgb  = (u16*)carve(384 * 512 * 2);
  u16*   Wib  = (u16*)carve(384 * 2048 * 2);
  u16*   Wab  = (u16*)carve(384 * 1024 * 2);
  u16*   Wrlb = (u16*)carve(384 * 1024 * 2);

  hipMemsetAsync(deg, 0, NN * 4, stream);
  hipMemsetAsync(cursor, 0, NN * 4, stream);

  const int eg = (NE + 255) / 256;
  k_hist<<<eg, 256, 0, stream>>>(ei + NE, deg);
  k_scan<<<1, 1024, 0, stream>>>(deg, row_ptr, inv_deg);
  k_scatter<<<eg, 256, 0, stream>>>(ei, ei + NE, row_ptr, cursor, csr_col);

  const int n8 = NN * DD / 8;
  k_cvt<<<(n8 + 255) / 256, 256, 0, stream>>>(x, x_bf, n8);

  k_cvt_pad<<<(512*512 + 255)/256, 256, 0, stream>>>(Wl1, Wl1b, 512, 512, 512*512, 512);
  k_cvt_pad<<<(512*512 + 255)/256, 256, 0, stream>>>(Wr1, Wr1b, 512, 512, 512*512, 512);
  k_cvt_pad<<<(512*512 + 255)/256, 256, 0, stream>>>(Wl2, Wl2b, 512, 512, 512*512, 512);
  k_cvt_pad<<<(512*512 + 255)/256, 256, 0, stream>>>(Wr2, Wr2b, 512, 512, 512*512, 512);
  k_cvt_pad<<<(512*512 + 255)/256, 256, 0, stream>>>(Wl3, Wl3b, 512, 512, 512*512, 512);
  k_cvt_pad<<<(512*512 + 255)/256, 256, 0, stream>>>(Wr3, Wr3b, 512, 512, 512*512, 512);
  k_cvt_pad<<<(384*512 + 255)/256, 256, 0, stream>>>(Wg,  Wgb, 300, 512,  384*512,  512);
  k_cvt_pad<<<(384*2048+ 255)/256, 256, 0, stream>>>(Wi,  Wib, 300, 2048, 384*2048, 2048);
  k_cvt_pad<<<(384*1024+ 255)/256, 256, 0, stream>>>(Wa,  Wab, 300, 1000, 384*1024, 1024);
  k_cvt_pad<<<(384*1024+ 255)/256, 256, 0, stream>>>(Wrl, Wrlb,300, 1000, 384*1024, 1024);

  const dim3 gemm_grid(235, 4);
  // layer 1
  k_agg<<<7500, 256, 0, stream>>>(x_bf, row_ptr, csr_col, inv_deg, aggb);
  k_sage_gemm<<<gemm_grid, 256, 0, stream>>>(aggb, Wl1b, x_bf, Wr1b, b1, hA, nullptr, 1);
  // layer 2
  k_agg<<<7500, 256, 0, stream>>>(hA, row_ptr, csr_col, inv_deg, aggb);
  k_sage_gemm<<<gemm_grid, 256, 0, stream>>>(aggb, Wl2b, hA, Wr2b, b2, hB, nullptr, 1);
  // layer 3 (h output, no relu); bf16 copy goes into x_bf (reuse)
  k_agg<<<7500, 256, 0, stream>>>(hB, row_ptr, csr_col, inv_deg, aggb);
  k_sage_gemm<<<gemm_grid, 256, 0, stream>>>(aggb, Wl3b, hB, Wr3b, b3, x_bf, out + OUT_H, 0);

  // fusion projections: grid (469,2), BM=64, BN=192
  const dim3 fuse_grid(469, 2);
  k_fuse_gemm<1><<<fuse_grid, 256, 0, stream>>>((const void*)x_bf,    512,  512,  Wgb,  bg,  gph);
  k_fuse_gemm<0><<<fuse_grid, 256, 0, stream>>>((const void*)img_emb, 2048, 2048, Wib,  bi,  out + OUT_IMG);
  k_fuse_gemm<0><<<fuse_grid, 256, 0, stream>>>((const void*)attr_emb,1000, 1024, Wab,  ba,  out + OUT_ATTR);
  k_fuse_gemm<0><<<fuse_grid, 256, 0, stream>>>((const void*)rel_emb, 1000, 1024, Wrlb, brl, out + OUT_REL);

  // gated fusion + normalize
  k_fuse_final<<<7500, 256, 0, stream>>>(gph, out + OUT_IMG, out + OUT_ATTR, out + OUT_REL,
                                         Wfp, bfp, out + OUT_FUSED);
}

// Round 4
// 922.890 us; speedup vs baseline: 1.6934x; 1.6934x over previous
//
#include <hip/hip_runtime.h>

typedef unsigned short u16;
typedef unsigned int   u32;
typedef __attribute__((ext_vector_type(8))) __bf16 bf16x8;
typedef __attribute__((ext_vector_type(4))) float  f32x4;

#define DEV __device__ __forceinline__

static constexpr int NN = 30000;
static constexpr int NE = 480000;
static constexpr int DD = 512;

static constexpr long OUT_FUSED = 0;
static constexpr long OUT_H     = 9000000;
static constexpr long OUT_IMG   = 24360000;
static constexpr long OUT_ATTR  = 33360000;
static constexpr long OUT_REL   = 42360000;

DEV float bf2f(u32 u){ u32 v = u << 16; float f; __builtin_memcpy(&f, &v, 4); return f; }
DEV u16 f2bf(float f){ u32 u; __builtin_memcpy(&u, &f, 4); u = (u + 0x7fffu + ((u >> 16) & 1u)) >> 16; return (u16)u; }
DEV u32 pk2(float a, float b){ return (u32)f2bf(a) | ((u32)f2bf(b) << 16); }

DEV void gll16(const void* g, void* l){
  __builtin_amdgcn_global_load_lds((const __attribute__((address_space(1))) void*)g,
                                   (__attribute__((address_space(3))) void*)l, 16, 0, 0);
}

// ---------------- CSR build ----------------
__global__ void k_hist(const int* __restrict__ dst, int* __restrict__ deg){
  int e = blockIdx.x * 256 + threadIdx.x;
  if (e < NE) atomicAdd(&deg[dst[e]], 1);
}

__global__ void k_scan(const int* __restrict__ deg, int* __restrict__ rp, float* __restrict__ invd){
  __shared__ int sh[1024];
  __shared__ int carry_s;
  const int tid = threadIdx.x;
  if (tid == 0) carry_s = 0;
  __syncthreads();
  for (int base = 0; base < NN; base += 1024){
    int i = base + tid;
    int v = (i < NN) ? deg[i] : 0;
    sh[tid] = v;
    __syncthreads();
    for (int off = 1; off < 1024; off <<= 1){
      int t = (tid >= off) ? sh[tid - off] : 0;
      __syncthreads();
      sh[tid] += t;
      __syncthreads();
    }
    int incl = sh[tid];
    int c = carry_s;
    if (i < NN){
      rp[i]   = c + incl - v;
      invd[i] = 1.0f / (float)(v > 1 ? v : 1);
    }
    __syncthreads();
    if (tid == 1023) carry_s = c + incl;
    __syncthreads();
  }
  if (tid == 0) rp[NN] = carry_s;
}

__global__ void k_scatter(const int* __restrict__ src, const int* __restrict__ dst,
                          const int* __restrict__ rp, int* __restrict__ cur, int* __restrict__ col){
  int e = blockIdx.x * 256 + threadIdx.x;
  if (e >= NE) return;
  int d = dst[e];
  int p = atomicAdd(&cur[d], 1);
  col[rp[d] + p] = src[e];
}

// ---------------- converts ----------------
__global__ void k_cvt(const float* __restrict__ src, u16* __restrict__ dst, const int n8){
  int i = blockIdx.x * 256 + threadIdx.x;
  if (i >= n8) return;
  const float4* s4 = (const float4*)src;
  float4 p = s4[2*i], q = s4[2*i+1];
  uint4 o; o.x = pk2(p.x,p.y); o.y = pk2(p.z,p.w); o.z = pk2(q.x,q.y); o.w = pk2(q.z,q.w);
  ((uint4*)dst)[i] = o;
}

__global__ void k_cvt_pad(const float* __restrict__ src, u16* __restrict__ dst,
                          const int rows, const int K, const int total, const int Kp){
  int i = blockIdx.x * 256 + threadIdx.x;
  if (i >= total) return;
  int r = i / Kp, k = i - r * Kp;
  float v = (r < rows && k < K) ? src[r * K + k] : 0.f;
  dst[i] = f2bf(v);
}

// ---------------- mean aggregation (one wave per node) ----------------
__global__ __launch_bounds__(256) void k_agg(const u16* __restrict__ Xb, const int* __restrict__ rp,
        const int* __restrict__ cols, const float* __restrict__ invd, u16* __restrict__ aggb)
{
  const int node = blockIdx.x * 4 + (threadIdx.x >> 6);
  const int l = threadIdx.x & 63;
  const int beg = rp[node], end = rp[node + 1];
  float a0=0,a1=0,a2=0,a3=0,a4=0,a5=0,a6=0,a7=0;
  const uint4* X4 = (const uint4*)Xb;
  for (int e = beg; e < end; ++e){
    const int s = cols[e];
    uint4 v = X4[s * 64 + l];
    a0 += bf2f(v.x & 0xffffu); a1 += bf2f(v.x >> 16);
    a2 += bf2f(v.y & 0xffffu); a3 += bf2f(v.y >> 16);
    a4 += bf2f(v.z & 0xffffu); a5 += bf2f(v.z >> 16);
    a6 += bf2f(v.w & 0xffffu); a7 += bf2f(v.w >> 16);
  }
  const float sc = invd[node];
  uint4 o;
  o.x = pk2(a0*sc, a1*sc); o.y = pk2(a2*sc, a3*sc);
  o.z = pk2(a4*sc, a5*sc); o.w = pk2(a6*sc, a7*sc);
  ((uint4*)aggb)[node * 64 + l] = o;
}

// ---------------- SAGE GEMM (R0-proven m97 structure): C = A1@W1^T + A2@W2^T + bias ----------------
__global__ __launch_bounds__(256) void k_sage_gemm(
    const u16* __restrict__ A1, const u16* __restrict__ W1,
    const u16* __restrict__ A2, const u16* __restrict__ W2,
    const float* __restrict__ bias,
    u16* __restrict__ outB, float* __restrict__ outF, const int relu)
{
  __shared__ u16 lA[2][128 * 32];
  __shared__ u16 lB[2][128 * 32];
  const int tid = threadIdx.x;
  const int w = tid >> 6, l = tid & 63;
  const int brow = blockIdx.x * 128, bcol = blockIdx.y * 128;

  f32x4 acc[4][4];
  #pragma unroll
  for (int i = 0; i < 4; ++i)
    #pragma unroll
    for (int j = 0; j < 4; ++j) acc[i][j] = {0.f, 0.f, 0.f, 0.f};

  const int srow  = tid >> 2;
  const int kpart = (tid & 3) * 8;
  int g0 = brow + srow;      if (g0 >= NN) g0 = NN - 1;
  int g1 = brow + 64 + srow; if (g1 >= NN) g1 = NN - 1;

  auto stage = [&](int buf, int kt){
    const u16 *A, *W; int kk;
    if (kt < 16){ A = A1; W = W1; kk = kt * 32; } else { A = A2; W = W2; kk = (kt - 16) * 32; }
    gll16(A + (size_t)g0 * DD + kk + kpart, &lA[buf][(w * 16) * 32]);
    gll16(A + (size_t)g1 * DD + kk + kpart, &lA[buf][(64 + w * 16) * 32]);
    gll16(W + (size_t)(bcol + srow) * DD + kk + kpart,      &lB[buf][(w * 16) * 32]);
    gll16(W + (size_t)(bcol + 64 + srow) * DD + kk + kpart, &lB[buf][(64 + w * 16) * 32]);
  };

  stage(0, 0);
  __syncthreads();
  int cur = 0;
  for (int kt = 0; kt < 32; ++kt){
    if (kt + 1 < 32) stage(cur ^ 1, kt + 1);
    const u16* As = &lA[cur][((w & 1) * 64 + (l & 15)) * 32 + (l >> 4) * 8];
    const u16* Bs = &lB[cur][((w >> 1) * 64 + (l & 15)) * 32 + (l >> 4) * 8];
    bf16x8 a[4], b[4];
    #pragma unroll
    for (int i = 0; i < 4; ++i) a[i] = *(const bf16x8*)(As + i * 512);
    #pragma unroll
    for (int j = 0; j < 4; ++j) b[j] = *(const bf16x8*)(Bs + j * 512);
    #pragma unroll
    for (int i = 0; i < 4; ++i)
      #pragma unroll
      for (int j = 0; j < 4; ++j)
        acc[i][j] = __builtin_amdgcn_mfma_f32_16x16x32_bf16(a[i], b[j], acc[i][j], 0, 0, 0);
    __syncthreads();
    cur ^= 1;
  }

  const int wm = (w & 1) * 64, wn = (w >> 1) * 64;
  #pragma unroll
  for (int j = 0; j < 4; ++j){
    const int col = bcol + wn + j * 16 + (l & 15);
    const float bv = bias[col];
    #pragma unroll
    for (int i = 0; i < 4; ++i){
      const int row0 = brow + wm + i * 16 + ((l >> 4) << 2);
      #pragma unroll
      for (int r = 0; r < 4; ++r){
        const int row = row0 + r;
        if (row < NN){
          float v = acc[i][j][r] + bv;
          if (relu) v = fmaxf(v, 0.f);
          outB[(size_t)row * DD + col] = f2bf(v);
          if (outF) outF[(size_t)row * DD + col] = v;
        }
      }
    }
  }
}

// ---------------- Fusion GEMM: C[M,300] = A@W^T + bias ----------------
// BM=64, BN=320 (single N tile: A streamed once), BK=32, 4 waves, grid=469.
// B via global_load_lds; A via T14-lite reg path (f32->bf16) or gll (bf16).
template<int AKIND> // 0: f32 A, 1: bf16 A
__global__ __launch_bounds__(256) void k_fuse_gemm(
    const void* __restrict__ Asrc, const int K, const int Kp,
    const u16* __restrict__ Wp, const float* __restrict__ bias, float* __restrict__ outC)
{
  __shared__ u16 lA[2][64 * 32];
  __shared__ u16 lB[2][320 * 32];
  const int tid = threadIdx.x;
  const int w = tid >> 6, l = tid & 63;
  const int brow = blockIdx.x * 64;
  const int NT = Kp >> 5;

  f32x4 acc[4][5];
  #pragma unroll
  for (int i = 0; i < 4; ++i)
    #pragma unroll
    for (int j = 0; j < 5; ++j) acc[i][j] = {0.f, 0.f, 0.f, 0.f};

  const int arow = tid >> 2;        // 0..63
  const int agr  = tid & 3;         // 16B group
  int garow = brow + arow; if (garow >= NN) garow = NN - 1;

  // B: 5 gll slots/thread; slot s = tid + 256*is -> row s>>2, grp s&3; LDS linear = s*16B
  auto stageB = [&](int buf, int kt){
    const int kk = kt * 32;
    #pragma unroll
    for (int is = 0; is < 5; ++is){
      const int s = tid + 256 * is;
      gll16(Wp + (size_t)(s >> 2) * Kp + kk + (s & 3) * 8,
            &lB[buf][(w * 64 + 256 * is) * 16 / 2]);   // u16 units: (w*64+256*is)*8
    }
  };

  float4 pa, qa; uint4 ab;
  auto loadA = [&](int kt){
    if (AKIND == 0){
      const float* A = (const float*)Asrc + (size_t)garow * K;
      const int k0 = kt * 32 + agr * 8;
      if (k0 + 8 <= K){
        pa = *(const float4*)(A + k0);
        qa = *(const float4*)(A + k0 + 4);
      } else {
        float e[8];
        #pragma unroll
        for (int t = 0; t < 8; ++t){ int k = k0 + t; e[t] = (k < K) ? A[k] : 0.f; }
        pa.x=e[0]; pa.y=e[1]; pa.z=e[2]; pa.w=e[3];
        qa.x=e[4]; qa.y=e[5]; qa.z=e[6]; qa.w=e[7];
      }
    } else {
      ab = *(const uint4*)((const u16*)Asrc + (size_t)garow * Kp + kt * 32 + agr * 8);
    }
  };
  auto writeA = [&](int buf){
    uint4 t;
    if (AKIND == 0){
      t.x = pk2(pa.x, pa.y); t.y = pk2(pa.z, pa.w);
      t.z = pk2(qa.x, qa.y); t.w = pk2(qa.z, qa.w);
    } else t = ab;
    *(uint4*)&lA[buf][arow * 32 + agr * 8] = t;
  };

  loadA(0); writeA(0);
  stageB(0, 0);
  __syncthreads();

  int cur = 0;
  for (int kt = 0; kt < NT; ++kt){
    const bool pf = (kt + 1 < NT);
    if (pf){
      loadA(kt + 1);
      stageB(cur ^ 1, kt + 1);
    }
    const u16* As = &lA[cur][(l & 15) * 32 + (l >> 4) * 8];
    const u16* Bs = &lB[cur][(w * 80 + (l & 15)) * 32 + (l >> 4) * 8];
    bf16x8 a[4], b[5];
    #pragma unroll
    for (int i = 0; i < 4; ++i) a[i] = *(const bf16x8*)(As + i * 512);
    #pragma unroll
    for (int j = 0; j < 5; ++j) b[j] = *(const bf16x8*)(Bs + j * 512);
    #pragma unroll
    for (int i = 0; i < 4; ++i)
      #pragma unroll
      for (int j = 0; j < 5; ++j)
        acc[i][j] = __builtin_amdgcn_mfma_f32_16x16x32_bf16(a[i], b[j], acc[i][j], 0, 0, 0);
    if (pf) writeA(cur ^ 1);
    __syncthreads();
    cur ^= 1;
  }

  #pragma unroll
  for (int j = 0; j < 5; ++j){
    const int col = w * 80 + j * 16 + (l & 15);
    if (col < 300){
      const float bv = bias[col];
      #pragma unroll
      for (int i = 0; i < 4; ++i){
        const int row0 = brow + i * 16 + ((l >> 4) << 2);
        #pragma unroll
        for (int r = 0; r < 4; ++r){
          const int row = row0 + r;
          if (row < NN) outC[(size_t)row * 300 + col] = acc[i][j][r] + bv;
        }
      }
    }
  }
}

// ---------------- gates + softmax + weighted sum + L2 norm (one wave per node) ----------------
__global__ __launch_bounds__(256) void k_fuse_final(
    const float* __restrict__ gph, const float* __restrict__ img,
    const float* __restrict__ attr, const float* __restrict__ rel,
    const float* __restrict__ Wfp, const float* __restrict__ bfp,
    float* __restrict__ fused)
{
  const int node = blockIdx.x * 4 + (threadIdx.x >> 6);
  const int l = threadIdx.x & 63;
  const size_t base = (size_t)node * 300;

  float e0[5], e1[5], e2[5], e3[5];
  float p0 = 0, p1 = 0, p2 = 0, p3 = 0;
  #pragma unroll
  for (int s = 0; s < 5; ++s){
    const int c = l + s * 64;
    const bool ok = (c < 300);
    const float wf = ok ? Wfp[c] : 0.f;
    const float a = ok ? gph[base + c]  : 0.f;
    const float b = ok ? img[base + c]  : 0.f;
    const float cc= ok ? attr[base + c] : 0.f;
    const float d = ok ? rel[base + c]  : 0.f;
    e0[s] = a; e1[s] = b; e2[s] = cc; e3[s] = d;
    p0 += wf * a; p1 += wf * b; p2 += wf * cc; p3 += wf * d;
  }
  #pragma unroll
  for (int off = 32; off >= 1; off >>= 1){
    p0 += __shfl_xor(p0, off); p1 += __shfl_xor(p1, off);
    p2 += __shfl_xor(p2, off); p3 += __shfl_xor(p3, off);
  }
  const float bb = bfp[0];
  const float g0 = p0 + bb, g1 = p1 + bb, g2 = p2 + bb, g3 = p3 + bb;
  const float m = fmaxf(fmaxf(g0, g1), fmaxf(g2, g3));
  float w0 = expf(g0 - m), w1 = expf(g1 - m), w2 = expf(g2 - m), w3 = expf(g3 - m);
  const float inv = 1.f / (w0 + w1 + w2 + w3);
  w0 *= inv; w1 *= inv; w2 *= inv; w3 *= inv;

  float f[5]; float nsq = 0;
  #pragma unroll
  for (int s = 0; s < 5; ++s){
    f[s] = w0 * e0[s] + w1 * e1[s] + w2 * e2[s] + w3 * e3[s];
    nsq += f[s] * f[s];
  }
  #pragma unroll
  for (int off = 32; off >= 1; off >>= 1) nsq += __shfl_xor(nsq, off);
  float nrm = sqrtf(nsq); nrm = fmaxf(nrm, 1e-12f);
  const float innv = 1.f / nrm;
  #pragma unroll
  for (int s = 0; s < 5; ++s){
    const int c = l + s * 64;
    if (c < 300) fused[base + c] = f[s] * innv;
  }
}

// ---------------- launch ----------------
extern "C" void kernel_launch(void* const* d_in, const int* in_sizes, int n_in,
                              void* d_out, int out_size, void* d_ws, size_t ws_size,
                              hipStream_t stream) {
  const float* x        = (const float*)d_in[0];
  const int*   ei       = (const int*)  d_in[1];
  const float* img_emb  = (const float*)d_in[2];
  const float* attr_emb = (const float*)d_in[3];
  const float* rel_emb  = (const float*)d_in[4];
  const float* Wl1 = (const float*)d_in[5],  *Wr1 = (const float*)d_in[6],  *b1 = (const float*)d_in[7];
  const float* Wl2 = (const float*)d_in[8],  *Wr2 = (const float*)d_in[9],  *b2 = (const float*)d_in[10];
  const float* Wl3 = (const float*)d_in[11], *Wr3 = (const float*)d_in[12], *b3 = (const float*)d_in[13];
  const float* Wg  = (const float*)d_in[14], *bg  = (const float*)d_in[15];
  const float* Wi  = (const float*)d_in[16], *bi  = (const float*)d_in[17];
  const float* Wa  = (const float*)d_in[18], *ba  = (const float*)d_in[19];
  const float* Wrl = (const float*)d_in[20], *brl = (const float*)d_in[21];
  const float* Wfp = (const float*)d_in[22], *bfp = (const float*)d_in[23];
  float* out = (float*)d_out;

  char* p = (char*)d_ws;
  auto carve = [&](size_t bytes) -> void* {
    void* r = (void*)p;
    p += (bytes + 255) & ~(size_t)255;
    return r;
  };
  int*   deg     = (int*)  carve(NN * 4);
  int*   cursor  = (int*)  carve(NN * 4);
  int*   row_ptr = (int*)  carve((NN + 1) * 4);
  float* inv_deg = (float*)carve(NN * 4);
  int*   csr_col = (int*)  carve(NE * 4);
  u16*   x_bf    = (u16*)  carve((size_t)NN * DD * 2);   // also reused for h3
  u16*   hA      = (u16*)  carve((size_t)NN * DD * 2);
  u16*   hB      = (u16*)  carve((size_t)NN * DD * 2);
  u16*   aggb    = (u16*)  carve((size_t)NN * DD * 2);
  float* gph     = (float*)carve((size_t)NN * 300 * 4);
  u16*   Wl1b = (u16*)carve(512 * 512 * 2);
  u16*   Wr1b = (u16*)carve(512 * 512 * 2);
  u16*   Wl2b = (u16*)carve(512 * 512 * 2);
  u16*   Wr2b = (u16*)carve(512 * 512 * 2);
  u16*   Wl3b = (u16*)carve(512 * 512 * 2);
  u16*   Wr3b = (u16*)carve(512 * 512 * 2);
  u16*   Wgb  = (u16*)carve(384 * 512 * 2);
  u16*   Wib  = (u16*)carve(384 * 2048 * 2);
  u16*   Wab  = (u16*)carve(384 * 1024 * 2);
  u16*   Wrlb = (u16*)carve(384 * 1024 * 2);

  hipMemsetAsync(deg, 0, NN * 4, stream);
  hipMemsetAsync(cursor, 0, NN * 4, stream);

  const int eg = (NE + 255) / 256;
  k_hist<<<eg, 256, 0, stream>>>(ei + NE, deg);
  k_scan<<<1, 1024, 0, stream>>>(deg, row_ptr, inv_deg);
  k_scatter<<<eg, 256, 0, stream>>>(ei, ei + NE, row_ptr, cursor, csr_col);

  const int n8 = NN * DD / 8;
  k_cvt<<<(n8 + 255) / 256, 256, 0, stream>>>(x, x_bf, n8);

  k_cvt_pad<<<(512*512 + 255)/256, 256, 0, stream>>>(Wl1, Wl1b, 512, 512, 512*512, 512);
  k_cvt_pad<<<(512*512 + 255)/256, 256, 0, stream>>>(Wr1, Wr1b, 512, 512, 512*512, 512);
  k_cvt_pad<<<(512*512 + 255)/256, 256, 0, stream>>>(Wl2, Wl2b, 512, 512, 512*512, 512);
  k_cvt_pad<<<(512*512 + 255)/256, 256, 0, stream>>>(Wr2, Wr2b, 512, 512, 512*512, 512);
  k_cvt_pad<<<(512*512 + 255)/256, 256, 0, stream>>>(Wl3, Wl3b, 512, 512, 512*512, 512);
  k_cvt_pad<<<(512*512 + 255)/256, 256, 0, stream>>>(Wr3, Wr3b, 512, 512, 512*512, 512);
  k_cvt_pad<<<(384*512 + 255)/256, 256, 0, stream>>>(Wg,  Wgb, 300, 512,  384*512,  512);
  k_cvt_pad<<<(384*2048+ 255)/256, 256, 0, stream>>>(Wi,  Wib, 300, 2048, 384*2048, 2048);
  k_cvt_pad<<<(384*1024+ 255)/256, 256, 0, stream>>>(Wa,  Wab, 300, 1000, 384*1024, 1024);
  k_cvt_pad<<<(384*1024+ 255)/256, 256, 0, stream>>>(Wrl, Wrlb,300, 1000, 384*1024, 1024);

  const dim3 gemm_grid(235, 4);
  // layer 1
  k_agg<<<7500, 256, 0, stream>>>(x_bf, row_ptr, csr_col, inv_deg, aggb);
  k_sage_gemm<<<gemm_grid, 256, 0, stream>>>(aggb, Wl1b, x_bf, Wr1b, b1, hA, nullptr, 1);
  // layer 2
  k_agg<<<7500, 256, 0, stream>>>(hA, row_ptr, csr_col, inv_deg, aggb);
  k_sage_gemm<<<gemm_grid, 256, 0, stream>>>(aggb, Wl2b, hA, Wr2b, b2, hB, nullptr, 1);
  // layer 3 (h output, no relu); bf16 copy goes into x_bf (reuse)
  k_agg<<<7500, 256, 0, stream>>>(hB, row_ptr, csr_col, inv_deg, aggb);
  k_sage_gemm<<<gemm_grid, 256, 0, stream>>>(aggb, Wl3b, hB, Wr3b, b3, x_bf, out + OUT_H, 0);

  // fusion projections: single N-tile (BN=320 covers 300), grid 469
  k_fuse_gemm<1><<<469, 256, 0, stream>>>((const void*)x_bf,    512,  512,  Wgb,  bg,  gph);
  k_fuse_gemm<0><<<469, 256, 0, stream>>>((const void*)img_emb, 2048, 2048, Wib,  bi,  out + OUT_IMG);
  k_fuse_gemm<0><<<469, 256, 0, stream>>>((const void*)attr_emb,1000, 1024, Wab,  ba,  out + OUT_ATTR);
  k_fuse_gemm<0><<<469, 256, 0, stream>>>((const void*)rel_emb, 1000, 1024, Wrlb, brl, out + OUT_REL);

  // gated fusion + normalize
  k_fuse_final<<<7500, 256, 0, stream>>>(gph, out + OUT_IMG, out + OUT_ATTR, out + OUT_REL,
                                         Wfp, bfp, out + OUT_FUSED);
}

// Round 5
// 871.846 us; speedup vs baseline: 1.7926x; 1.0585x over previous
//
#include <hip/hip_runtime.h>

typedef unsigned short u16;
typedef unsigned int   u32;
typedef __attribute__((ext_vector_type(8))) __bf16 bf16x8;
typedef __attribute__((ext_vector_type(4))) float  f32x4;

#define DEV __device__ __forceinline__

static constexpr int NN = 30000;
static constexpr int NE = 480000;
static constexpr int DD = 512;

static constexpr long OUT_FUSED = 0;
static constexpr long OUT_H     = 9000000;
static constexpr long OUT_IMG   = 24360000;
static constexpr long OUT_ATTR  = 33360000;
static constexpr long OUT_REL   = 42360000;

DEV float bf2f(u32 u){ u32 v = u << 16; float f; __builtin_memcpy(&f, &v, 4); return f; }
DEV u16 f2bf(float f){ u32 u; __builtin_memcpy(&u, &f, 4); u = (u + 0x7fffu + ((u >> 16) & 1u)) >> 16; return (u16)u; }
DEV u32 pk2(float a, float b){ return (u32)f2bf(a) | ((u32)f2bf(b) << 16); }

DEV void gll16(const void* g, void* l){
  __builtin_amdgcn_global_load_lds((const __attribute__((address_space(1))) void*)g,
                                   (__attribute__((address_space(3))) void*)l, 16, 0, 0);
}

// ---------------- CSR build ----------------
__global__ void k_hist(const int* __restrict__ dst, int* __restrict__ deg){
  int e = blockIdx.x * 256 + threadIdx.x;
  if (e < NE) atomicAdd(&deg[dst[e]], 1);
}

// chunk-per-thread scan: 22 barriers instead of ~600
__global__ void k_scan(const int* __restrict__ deg, int* __restrict__ rp, float* __restrict__ invd){
  __shared__ int sh[1024];
  const int t = threadIdx.x;
  const int base = t * 30;   // 1024*30 = 30720 >= NN
  int sum = 0;
  #pragma unroll
  for (int i = 0; i < 30; ++i){
    int idx = base + i;
    sum += (idx < NN) ? deg[idx] : 0;
  }
  sh[t] = sum;
  __syncthreads();
  for (int off = 1; off < 1024; off <<= 1){
    int vv = (t >= off) ? sh[t - off] : 0;
    __syncthreads();
    sh[t] += vv;
    __syncthreads();
  }
  int run = (t == 0) ? 0 : sh[t - 1];
  #pragma unroll
  for (int i = 0; i < 30; ++i){
    int idx = base + i;
    if (idx < NN){
      int v = deg[idx];
      rp[idx]   = run;
      invd[idx] = 1.0f / (float)(v > 1 ? v : 1);
      run += v;
    }
  }
  if (t == 1023) rp[NN] = run;
}

__global__ void k_scatter(const int* __restrict__ src, const int* __restrict__ dst,
                          const int* __restrict__ rp, int* __restrict__ cur, int* __restrict__ col){
  int e = blockIdx.x * 256 + threadIdx.x;
  if (e >= NE) return;
  int d = dst[e];
  int p = atomicAdd(&cur[d], 1);
  col[rp[d] + p] = src[e];
}

// ---------------- converts ----------------
__global__ void k_cvt(const float* __restrict__ src, u16* __restrict__ dst, const int n8){
  int i = blockIdx.x * 256 + threadIdx.x;
  if (i >= n8) return;
  const float4* s4 = (const float4*)src;
  float4 p = s4[2*i], q = s4[2*i+1];
  uint4 o; o.x = pk2(p.x,p.y); o.y = pk2(p.z,p.w); o.z = pk2(q.x,q.y); o.w = pk2(q.z,q.w);
  ((uint4*)dst)[i] = o;
}

// all 10 weight conversions in one launch; Kp is a power of two (shift/mask)
struct PadJob { const float* src; u16* dst; int rows, K, shift, total; };
struct PadJobs { PadJob j[10]; };
__global__ void k_cvt_pad_all(PadJobs js){
  const PadJob jb = js.j[blockIdx.y];
  const int km = (1 << jb.shift) - 1;
  for (int i = blockIdx.x * 256 + threadIdx.x; i < jb.total; i += gridDim.x * 256){
    int r = i >> jb.shift, k = i & km;
    float v = (r < jb.rows && k < jb.K) ? jb.src[(size_t)r * jb.K + k] : 0.f;
    jb.dst[i] = f2bf(v);
  }
}

// ---------------- mean aggregation (one wave per node, 4-deep MLP) ----------------
__global__ __launch_bounds__(256) void k_agg(const u16* __restrict__ Xb, const int* __restrict__ rp,
        const int* __restrict__ cols, const float* __restrict__ invd, u16* __restrict__ aggb)
{
  const int node = blockIdx.x * 4 + (threadIdx.x >> 6);
  const int l = threadIdx.x & 63;
  const int beg = rp[node], end = rp[node + 1];
  float a0=0,a1=0,a2=0,a3=0,a4=0,a5=0,a6=0,a7=0;
  const uint4* X4 = (const uint4*)Xb;
  auto accum = [&](uint4 v){
    a0 += bf2f(v.x & 0xffffu); a1 += bf2f(v.x >> 16);
    a2 += bf2f(v.y & 0xffffu); a3 += bf2f(v.y >> 16);
    a4 += bf2f(v.z & 0xffffu); a5 += bf2f(v.z >> 16);
    a6 += bf2f(v.w & 0xffffu); a7 += bf2f(v.w >> 16);
  };
  int e = beg;
  for (; e + 4 <= end; e += 4){
    const int s0 = cols[e], s1 = cols[e+1], s2 = cols[e+2], s3 = cols[e+3];
    uint4 v0 = X4[(size_t)s0 * 64 + l];
    uint4 v1 = X4[(size_t)s1 * 64 + l];
    uint4 v2 = X4[(size_t)s2 * 64 + l];
    uint4 v3 = X4[(size_t)s3 * 64 + l];
    accum(v0); accum(v1); accum(v2); accum(v3);
  }
  for (; e < end; ++e){
    const int s = cols[e];
    accum(X4[(size_t)s * 64 + l]);
  }
  const float sc = invd[node];
  uint4 o;
  o.x = pk2(a0*sc, a1*sc); o.y = pk2(a2*sc, a3*sc);
  o.z = pk2(a4*sc, a5*sc); o.w = pk2(a6*sc, a7*sc);
  ((uint4*)aggb)[(size_t)node * 64 + l] = o;
}

// ---------------- SAGE GEMM (m97 structure, XCD-chunked grid): C = A1@W1^T + A2@W2^T + bias ----------------
// 1D grid 940; bijective XCD chunking (m204) so the 4 N-blocks of each M-panel
// are consecutive within one XCD's chunk -> A-panel L2 reuse.
__global__ __launch_bounds__(256) void k_sage_gemm(
    const u16* __restrict__ A1, const u16* __restrict__ W1,
    const u16* __restrict__ A2, const u16* __restrict__ W2,
    const float* __restrict__ bias,
    u16* __restrict__ outB, float* __restrict__ outF, const int relu)
{
  __shared__ u16 lA[2][128 * 32];
  __shared__ u16 lB[2][128 * 32];
  const int tid = threadIdx.x;
  const int w = tid >> 6, l = tid & 63;

  // 940 = 8*117 + 4
  const int bid = blockIdx.x;
  const int q = 117, r = 4;
  const int xcd = bid & 7, idx = bid >> 3;
  const int c = (xcd < r ? xcd * (q + 1) : r * (q + 1) + (xcd - r) * q) + idx;
  const int brow = (c >> 2) * 128, bcol = (c & 3) * 128;

  f32x4 acc[4][4];
  #pragma unroll
  for (int i = 0; i < 4; ++i)
    #pragma unroll
    for (int j = 0; j < 4; ++j) acc[i][j] = {0.f, 0.f, 0.f, 0.f};

  const int srow  = tid >> 2;
  const int kpart = (tid & 3) * 8;
  int g0 = brow + srow;      if (g0 >= NN) g0 = NN - 1;
  int g1 = brow + 64 + srow; if (g1 >= NN) g1 = NN - 1;

  auto stage = [&](int buf, int kt){
    const u16 *A, *W; int kk;
    if (kt < 16){ A = A1; W = W1; kk = kt * 32; } else { A = A2; W = W2; kk = (kt - 16) * 32; }
    gll16(A + (size_t)g0 * DD + kk + kpart, &lA[buf][(w * 16) * 32]);
    gll16(A + (size_t)g1 * DD + kk + kpart, &lA[buf][(64 + w * 16) * 32]);
    gll16(W + (size_t)(bcol + srow) * DD + kk + kpart,      &lB[buf][(w * 16) * 32]);
    gll16(W + (size_t)(bcol + 64 + srow) * DD + kk + kpart, &lB[buf][(64 + w * 16) * 32]);
  };

  stage(0, 0);
  __syncthreads();
  int cur = 0;
  for (int kt = 0; kt < 32; ++kt){
    if (kt + 1 < 32) stage(cur ^ 1, kt + 1);
    const u16* As = &lA[cur][((w & 1) * 64 + (l & 15)) * 32 + (l >> 4) * 8];
    const u16* Bs = &lB[cur][((w >> 1) * 64 + (l & 15)) * 32 + (l >> 4) * 8];
    bf16x8 a[4], b[4];
    #pragma unroll
    for (int i = 0; i < 4; ++i) a[i] = *(const bf16x8*)(As + i * 512);
    #pragma unroll
    for (int j = 0; j < 4; ++j) b[j] = *(const bf16x8*)(Bs + j * 512);
    #pragma unroll
    for (int i = 0; i < 4; ++i)
      #pragma unroll
      for (int j = 0; j < 4; ++j)
        acc[i][j] = __builtin_amdgcn_mfma_f32_16x16x32_bf16(a[i], b[j], acc[i][j], 0, 0, 0);
    __syncthreads();
    cur ^= 1;
  }

  const int wm = (w & 1) * 64, wn = (w >> 1) * 64;
  #pragma unroll
  for (int j = 0; j < 4; ++j){
    const int col = bcol + wn + j * 16 + (l & 15);
    const float bv = bias[col];
    #pragma unroll
    for (int i = 0; i < 4; ++i){
      const int row0 = brow + wm + i * 16 + ((l >> 4) << 2);
      #pragma unroll
      for (int r2 = 0; r2 < 4; ++r2){
        const int row = row0 + r2;
        if (row < NN){
          float v = acc[i][j][r2] + bv;
          if (relu) v = fmaxf(v, 0.f);
          outB[(size_t)row * DD + col] = f2bf(v);
          if (outF) outF[(size_t)row * DD + col] = v;
        }
      }
    }
  }
}

// ---------------- Fusion GEMM: C[M,300] = A@W^T + bias ----------------
// BM=64, BN=320 (single N tile: A streamed once), BK=32, 4 waves, grid=469.
template<int AKIND> // 0: f32 A, 1: bf16 A
__global__ __launch_bounds__(256) void k_fuse_gemm(
    const void* __restrict__ Asrc, const int K, const int Kp,
    const u16* __restrict__ Wp, const float* __restrict__ bias, float* __restrict__ outC)
{
  __shared__ u16 lA[2][64 * 32];
  __shared__ u16 lB[2][320 * 32];
  const int tid = threadIdx.x;
  const int w = tid >> 6, l = tid & 63;
  const int brow = blockIdx.x * 64;
  const int NT = Kp >> 5;

  f32x4 acc[4][5];
  #pragma unroll
  for (int i = 0; i < 4; ++i)
    #pragma unroll
    for (int j = 0; j < 5; ++j) acc[i][j] = {0.f, 0.f, 0.f, 0.f};

  const int arow = tid >> 2;
  const int agr  = tid & 3;
  int garow = brow + arow; if (garow >= NN) garow = NN - 1;

  auto stageB = [&](int buf, int kt){
    const int kk = kt * 32;
    #pragma unroll
    for (int is = 0; is < 5; ++is){
      const int s = tid + 256 * is;
      gll16(Wp + (size_t)(s >> 2) * Kp + kk + (s & 3) * 8,
            &lB[buf][(w * 64 + 256 * is) * 8]);
    }
  };

  float4 pa, qa; uint4 ab;
  auto loadA = [&](int kt){
    if (AKIND == 0){
      const float* A = (const float*)Asrc + (size_t)garow * K;
      const int k0 = kt * 32 + agr * 8;
      if (k0 + 8 <= K){
        pa = *(const float4*)(A + k0);
        qa = *(const float4*)(A + k0 + 4);
      } else {
        float e[8];
        #pragma unroll
        for (int t = 0; t < 8; ++t){ int k = k0 + t; e[t] = (k < K) ? A[k] : 0.f; }
        pa.x=e[0]; pa.y=e[1]; pa.z=e[2]; pa.w=e[3];
        qa.x=e[4]; qa.y=e[5]; qa.z=e[6]; qa.w=e[7];
      }
    } else {
      ab = *(const uint4*)((const u16*)Asrc + (size_t)garow * Kp + kt * 32 + agr * 8);
    }
  };
  auto writeA = [&](int buf){
    uint4 t;
    if (AKIND == 0){
      t.x = pk2(pa.x, pa.y); t.y = pk2(pa.z, pa.w);
      t.z = pk2(qa.x, qa.y); t.w = pk2(qa.z, qa.w);
    } else t = ab;
    *(uint4*)&lA[buf][arow * 32 + agr * 8] = t;
  };

  loadA(0); writeA(0);
  stageB(0, 0);
  __syncthreads();

  int cur = 0;
  for (int kt = 0; kt < NT; ++kt){
    const bool pf = (kt + 1 < NT);
    if (pf){
      loadA(kt + 1);
      stageB(cur ^ 1, kt + 1);
    }
    const u16* As = &lA[cur][(l & 15) * 32 + (l >> 4) * 8];
    const u16* Bs = &lB[cur][(w * 80 + (l & 15)) * 32 + (l >> 4) * 8];
    bf16x8 a[4], b[5];
    #pragma unroll
    for (int i = 0; i < 4; ++i) a[i] = *(const bf16x8*)(As + i * 512);
    #pragma unroll
    for (int j = 0; j < 5; ++j) b[j] = *(const bf16x8*)(Bs + j * 512);
    #pragma unroll
    for (int i = 0; i < 4; ++i)
      #pragma unroll
      for (int j = 0; j < 5; ++j)
        acc[i][j] = __builtin_amdgcn_mfma_f32_16x16x32_bf16(a[i], b[j], acc[i][j], 0, 0, 0);
    if (pf) writeA(cur ^ 1);
    __syncthreads();
    cur ^= 1;
  }

  #pragma unroll
  for (int j = 0; j < 5; ++j){
    const int col = w * 80 + j * 16 + (l & 15);
    if (col < 300){
      const float bv = bias[col];
      #pragma unroll
      for (int i = 0; i < 4; ++i){
        const int row0 = brow + i * 16 + ((l >> 4) << 2);
        #pragma unroll
        for (int r = 0; r < 4; ++r){
          const int row = row0 + r;
          if (row < NN) outC[(size_t)row * 300 + col] = acc[i][j][r] + bv;
        }
      }
    }
  }
}

// ---------------- gates + softmax + weighted sum + L2 norm (one wave per node) ----------------
__global__ __launch_bounds__(256) void k_fuse_final(
    const float* __restrict__ gph, const float* __restrict__ img,
    const float* __restrict__ attr, const float* __restrict__ rel,
    const float* __restrict__ Wfp, const float* __restrict__ bfp,
    float* __restrict__ fused)
{
  const int node = blockIdx.x * 4 + (threadIdx.x >> 6);
  const int l = threadIdx.x & 63;
  const size_t base = (size_t)node * 300;

  float e0[5], e1[5], e2[5], e3[5];
  float p0 = 0, p1 = 0, p2 = 0, p3 = 0;
  #pragma unroll
  for (int s = 0; s < 5; ++s){
    const int c = l + s * 64;
    const bool ok = (c < 300);
    const float wf = ok ? Wfp[c] : 0.f;
    const float a = ok ? gph[base + c]  : 0.f;
    const float b = ok ? img[base + c]  : 0.f;
    const float cc= ok ? attr[base + c] : 0.f;
    const float d = ok ? rel[base + c]  : 0.f;
    e0[s] = a; e1[s] = b; e2[s] = cc; e3[s] = d;
    p0 += wf * a; p1 += wf * b; p2 += wf * cc; p3 += wf * d;
  }
  #pragma unroll
  for (int off = 32; off >= 1; off >>= 1){
    p0 += __shfl_xor(p0, off); p1 += __shfl_xor(p1, off);
    p2 += __shfl_xor(p2, off); p3 += __shfl_xor(p3, off);
  }
  const float bb = bfp[0];
  const float g0 = p0 + bb, g1 = p1 + bb, g2 = p2 + bb, g3 = p3 + bb;
  const float m = fmaxf(fmaxf(g0, g1), fmaxf(g2, g3));
  float w0 = expf(g0 - m), w1 = expf(g1 - m), w2 = expf(g2 - m), w3 = expf(g3 - m);
  const float inv = 1.f / (w0 + w1 + w2 + w3);
  w0 *= inv; w1 *= inv; w2 *= inv; w3 *= inv;

  float f[5]; float nsq = 0;
  #pragma unroll
  for (int s = 0; s < 5; ++s){
    f[s] = w0 * e0[s] + w1 * e1[s] + w2 * e2[s] + w3 * e3[s];
    nsq += f[s] * f[s];
  }
  #pragma unroll
  for (int off = 32; off >= 1; off >>= 1) nsq += __shfl_xor(nsq, off);
  float nrm = sqrtf(nsq); nrm = fmaxf(nrm, 1e-12f);
  const float innv = 1.f / nrm;
  #pragma unroll
  for (int s = 0; s < 5; ++s){
    const int c = l + s * 64;
    if (c < 300) fused[base + c] = f[s] * innv;
  }
}

// ---------------- launch ----------------
extern "C" void kernel_launch(void* const* d_in, const int* in_sizes, int n_in,
                              void* d_out, int out_size, void* d_ws, size_t ws_size,
                              hipStream_t stream) {
  const float* x        = (const float*)d_in[0];
  const int*   ei       = (const int*)  d_in[1];
  const float* img_emb  = (const float*)d_in[2];
  const float* attr_emb = (const float*)d_in[3];
  const float* rel_emb  = (const float*)d_in[4];
  const float* Wl1 = (const float*)d_in[5],  *Wr1 = (const float*)d_in[6],  *b1 = (const float*)d_in[7];
  const float* Wl2 = (const float*)d_in[8],  *Wr2 = (const float*)d_in[9],  *b2 = (const float*)d_in[10];
  const float* Wl3 = (const float*)d_in[11], *Wr3 = (const float*)d_in[12], *b3 = (const float*)d_in[13];
  const float* Wg  = (const float*)d_in[14], *bg  = (const float*)d_in[15];
  const float* Wi  = (const float*)d_in[16], *bi  = (const float*)d_in[17];
  const float* Wa  = (const float*)d_in[18], *ba  = (const float*)d_in[19];
  const float* Wrl = (const float*)d_in[20], *brl = (const float*)d_in[21];
  const float* Wfp = (const float*)d_in[22], *bfp = (const float*)d_in[23];
  float* out = (float*)d_out;

  char* p = (char*)d_ws;
  auto carve = [&](size_t bytes) -> void* {
    void* r = (void*)p;
    p += (bytes + 255) & ~(size_t)255;
    return r;
  };
  int*   deg     = (int*)  carve(NN * 4);
  int*   cursor  = (int*)  carve(NN * 4);
  int*   row_ptr = (int*)  carve((NN + 1) * 4);
  float* inv_deg = (float*)carve(NN * 4);
  int*   csr_col = (int*)  carve(NE * 4);
  u16*   x_bf    = (u16*)  carve((size_t)NN * DD * 2);   // also reused for h3
  u16*   hA      = (u16*)  carve((size_t)NN * DD * 2);
  u16*   hB      = (u16*)  carve((size_t)NN * DD * 2);
  u16*   aggb    = (u16*)  carve((size_t)NN * DD * 2);
  float* gph     = (float*)carve((size_t)NN * 300 * 4);
  u16*   Wl1b = (u16*)carve(512 * 512 * 2);
  u16*   Wr1b = (u16*)carve(512 * 512 * 2);
  u16*   Wl2b = (u16*)carve(512 * 512 * 2);
  u16*   Wr2b = (u16*)carve(512 * 512 * 2);
  u16*   Wl3b = (u16*)carve(512 * 512 * 2);
  u16*   Wr3b = (u16*)carve(512 * 512 * 2);
  u16*   Wgb  = (u16*)carve(384 * 512 * 2);
  u16*   Wib  = (u16*)carve(384 * 2048 * 2);
  u16*   Wab  = (u16*)carve(384 * 1024 * 2);
  u16*   Wrlb = (u16*)carve(384 * 1024 * 2);

  hipMemsetAsync(deg, 0, NN * 4, stream);
  hipMemsetAsync(cursor, 0, NN * 4, stream);

  const int eg = (NE + 255) / 256;
  k_hist<<<eg, 256, 0, stream>>>(ei + NE, deg);
  k_scan<<<1, 1024, 0, stream>>>(deg, row_ptr, inv_deg);
  k_scatter<<<eg, 256, 0, stream>>>(ei, ei + NE, row_ptr, cursor, csr_col);

  const int n8 = NN * DD / 8;
  k_cvt<<<(n8 + 255) / 256, 256, 0, stream>>>(x, x_bf, n8);

  PadJobs js;
  js.j[0] = { Wl1, Wl1b, 512, 512,  9,  512*512 };
  js.j[1] = { Wr1, Wr1b, 512, 512,  9,  512*512 };
  js.j[2] = { Wl2, Wl2b, 512, 512,  9,  512*512 };
  js.j[3] = { Wr2, Wr2b, 512, 512,  9,  512*512 };
  js.j[4] = { Wl3, Wl3b, 512, 512,  9,  512*512 };
  js.j[5] = { Wr3, Wr3b, 512, 512,  9,  512*512 };
  js.j[6] = { Wg,  Wgb,  300, 512,  9,  384*512 };
  js.j[7] = { Wi,  Wib,  300, 2048, 11, 384*2048 };
  js.j[8] = { Wa,  Wab,  300, 1000, 10, 384*1024 };
  js.j[9] = { Wrl, Wrlb, 300, 1000, 10, 384*1024 };
  k_cvt_pad_all<<<dim3(384, 10), 256, 0, stream>>>(js);

  // layer 1
  k_agg<<<7500, 256, 0, stream>>>(x_bf, row_ptr, csr_col, inv_deg, aggb);
  k_sage_gemm<<<940, 256, 0, stream>>>(aggb, Wl1b, x_bf, Wr1b, b1, hA, nullptr, 1);
  // layer 2
  k_agg<<<7500, 256, 0, stream>>>(hA, row_ptr, csr_col, inv_deg, aggb);
  k_sage_gemm<<<940, 256, 0, stream>>>(aggb, Wl2b, hA, Wr2b, b2, hB, nullptr, 1);
  // layer 3 (h output, no relu); bf16 copy goes into x_bf (reuse)
  k_agg<<<7500, 256, 0, stream>>>(hB, row_ptr, csr_col, inv_deg, aggb);
  k_sage_gemm<<<940, 256, 0, stream>>>(aggb, Wl3b, hB, Wr3b, b3, x_bf, out + OUT_H, 0);

  // fusion projections: single N-tile (BN=320 covers 300), grid 469
  k_fuse_gemm<1><<<469, 256, 0, stream>>>((const void*)x_bf,    512,  512,  Wgb,  bg,  gph);
  k_fuse_gemm<0><<<469, 256, 0, stream>>>((const void*)img_emb, 2048, 2048, Wib,  bi,  out + OUT_IMG);
  k_fuse_gemm<0><<<469, 256, 0, stream>>>((const void*)attr_emb,1000, 1024, Wab,  ba,  out + OUT_ATTR);
  k_fuse_gemm<0><<<469, 256, 0, stream>>>((const void*)rel_emb, 1000, 1024, Wrlb, brl, out + OUT_REL);

  // gated fusion + normalize
  k_fuse_final<<<7500, 256, 0, stream>>>(gph, out + OUT_IMG, out + OUT_ATTR, out + OUT_REL,
                                         Wfp, bfp, out + OUT_FUSED);
}